// Round 21
// baseline (177.134 us; speedup 1.0000x reference)
//
#include <hip/hip_runtime.h>
#include <hip/hip_bf16.h>

#define B_ 128
#define S_ 196
#define E_ 768
#define M_ 768
#define KTOT (S_*E_)            // 150528
#define BK 256                  // k per superstep
#define SS_TOTAL (KTOT/BK)      // 588
#define KSPLIT 32
#define BN 48                   // m-rows per workgroup
#define MTN (M_/BN)             // 16
#define PITCH 528               // LDS row pitch bytes (16*odd -> staggered quads)
#define ZC 4                    // z-chunks in reduce

typedef __bf16 bf16x8 __attribute__((ext_vector_type(8)));
typedef __bf16 bf16x4 __attribute__((ext_vector_type(4)));
typedef float  f32x4  __attribute__((ext_vector_type(4)));

__device__ inline bf16x8 cvt8(const float* __restrict__ p) {
    float4 a = *(const float4*)p;
    float4 b = *(const float4*)(p + 4);
    bf16x8 r;
    r[0] = (__bf16)a.x; r[1] = (__bf16)a.y; r[2] = (__bf16)a.z; r[3] = (__bf16)a.w;
    r[4] = (__bf16)b.x; r[5] = (__bf16)b.y; r[6] = (__bf16)b.z; r[7] = (__bf16)b.w;
    return r;
}

// Barrier WITHOUT the implicit vmcnt(0) drain __syncthreads() carries.
__device__ inline void barrier_nodrain() {
    asm volatile("s_waitcnt lgkmcnt(0)" ::: "memory");
    __builtin_amdgcn_s_barrier();
}

// ---------------- prep: init_out | event_pool | pack_a (block-partitioned) ----
__global__ void prep(const float* __restrict__ mlp_b,
                     const float* __restrict__ fk_b,
                     const float* __restrict__ A,
                     const int* __restrict__ BE, int be_stride,
                     float* __restrict__ out,
                     float* __restrict__ EP,
                     __bf16* __restrict__ Apk) {
    const int bid = blockIdx.x;
    if (bid < 384) {
        int i = bid * 256 + threadIdx.x;
        int m = i % M_;
        out[i] = 0.9f * mlp_b[m] + 0.1f * fk_b[m];
    } else if (bid < 512) {
        int b = bid - 384;
        int s1 = BE[(b*4 + 0) * be_stride];
        int e1 = BE[(b*4 + 1) * be_stride];
        int s2 = BE[(b*4 + 2) * be_stride];
        int e2 = BE[(b*4 + 3) * be_stride];
        float inv1 = 1.0f / (float)(e1 - s1);
        float inv2 = 1.0f / (float)(e2 - s2);
        for (int c = threadIdx.x; c < E_; c += 256) {
            float sum1 = 0.f, sum2 = 0.f;
            for (int s = s1; s < e1; ++s) sum1 += A[((size_t)b * S_ + s) * E_ + c];
            for (int s = s2; s < e2; ++s) sum2 += A[((size_t)b * S_ + s) * E_ + c];
            EP[b * (2*E_) + c]       = sum1 * inv1;
            EP[b * (2*E_) + E_ + c]  = sum2 * inv2;
        }
    } else {
        const int nchunk = SS_TOTAL * 8 * 8 * 64;   // 2,408,448
        for (int c = (bid - 512) * 256 + threadIdx.x; c < nchunk; c += 3072 * 256) {
            int lane = c & 63;
            int kf   = (c >> 6) & 7;
            int bt   = (c >> 9) & 7;
            int ss   = c >> 12;
            int b = bt * 16 + (lane & 15);
            int k = ss * BK + kf * 32 + (lane >> 4) * 8;
            *(bf16x8*)(Apk + (size_t)c * 8) = cvt8(A + (size_t)b * KTOT + k);
        }
    }
}

// ---------------- fk_gemm: partial[kz][b][m] ------------------------------
// R14 structure; single theory change: W row-visits fetch 2 KB CONTIGUOUS
// (ss-pair, two back-to-back 1KB wave-loads into w0/w1) instead of 1 KB per
// phase -- halves DRAM row activations per byte for the 24.6k-stream W read
// (the remaining unexplained ~40% of fk time per the R18 probe). A ping-pong
// dropped (null per R10/R11) to keep ~105 VGPR under the forced 128 budget.

#define LOAD_A(sl)                                                            \
    _Pragma("unroll")                                                         \
    for (int kf = 0; kf < 8; ++kf)                                            \
        aA[kf] = *(const bf16x8*)(abase + (size_t)(sl) * 32768 + kf * 512);

#define LOAD_PAIR(sl)                                                         \
    _Pragma("unroll")                                                         \
    for (int i = 0; i < 6; ++i) {                                             \
        w0[i] = *(const float4*)(wbase + (size_t)i * KTOT + (size_t)(sl) * BK);\
        w1[i] = *(const float4*)(wbase + (size_t)i * KTOT + (size_t)(sl) * BK + BK);\
    }

#define LOAD_ONE(WREG, sl)                                                    \
    _Pragma("unroll")                                                         \
    for (int i = 0; i < 6; ++i)                                               \
        WREG[i] = *(const float4*)(wbase + (size_t)i * KTOT + (size_t)(sl) * BK);

#define WRITE_W(WREG, buf)                                                    \
    _Pragma("unroll")                                                         \
    for (int i = 0; i < 6; ++i) {                                             \
        bf16x4 h;                                                             \
        h[0] = (__bf16)WREG[i].x; h[1] = (__bf16)WREG[i].y;                   \
        h[2] = (__bf16)WREG[i].z; h[3] = (__bf16)WREG[i].w;                   \
        *(bf16x4*)(&Wlds[buf][0] + wb + i * PITCH) = h;                       \
    }

#define COMPUTE(buf)                                                          \
    _Pragma("unroll")                                                         \
    for (int kf = 0; kf < 8; ++kf) {                                          \
        _Pragma("unroll")                                                     \
        for (int n = 0; n < 3; ++n) {                                         \
            bf16x8 wf = *(const bf16x8*)(&Wlds[buf][0] +                      \
                        (n * 16 + r16) * PITCH + kf * 64 + kg * 16);          \
            acc[n] = __builtin_amdgcn_mfma_f32_16x16x32_bf16(aA[kf], wf,      \
                                                             acc[n], 0, 0, 0);\
        }                                                                     \
    }

__global__
__attribute__((amdgpu_flat_work_group_size(512, 512), amdgpu_waves_per_eu(4, 4)))
void fk_gemm(const __bf16* __restrict__ Apk,
             const float* __restrict__ W,
             float* __restrict__ partial) {
    __shared__ __align__(16) char Wlds[2][BN * PITCH];  // 2 x 25,344 B

    const int wg   = blockIdx.x;        // 0..511
    const int xcd  = wg & 7;            // wg -> XCD round-robin (m09)
    const int slot = wg >> 3;           // 0..63 per-XCD sequence
    const int kz   = (slot >> 4) * 8 + xcd;  // 4 kz groups per XCD
    const int mt   = slot & 15;         // 16 mt-wgs per kz, dispatch-adjacent
    const int ss0 = (SS_TOTAL * kz) / KSPLIT;
    const int SSN = (SS_TOTAL * (kz + 1)) / KSPLIT - ss0;   // 18 or 19

    const int tid = threadIdx.x;
    const int wv  = tid >> 6;           // 0..7 = b-tile
    const int lane = tid & 63;
    const int r16 = lane & 15;
    const int kg  = lane >> 4;

    const float*  wbase = W + (size_t)(mt * BN + wv * 6) * KTOT
                            + (size_t)ss0 * BK + lane * 4;
    const int     wb    = (wv * 6) * PITCH + lane * 8;
    const __bf16* abase = Apk + ((size_t)ss0 * 8 + wv) * 4096 + lane * 8;

    f32x4 acc[3] = {};
    float4 w0[6], w1[6];
    bf16x8 aA[8];

    // prologue: 2KB burst for ss {0,1}; stage both buffers
    LOAD_PAIR(0)
    WRITE_W(w0, 0)
    WRITE_W(w1, 1)
    barrier_nodrain();

    const int P = SSN >> 1;             // full pairs
    for (int p = 0; p < P; ++p) {
        const int nxt = 2 * p + 2;
        // issue next pair's 2KB-contiguous burst (in flight during compute)
        if (nxt + 1 < SSN)      { LOAD_PAIR(nxt) }
        else if (nxt < SSN)     { LOAD_ONE(w0, nxt) }
        // compute both sub-steps of this pair
        LOAD_A(2 * p)
        COMPUTE(0)
        LOAD_A(2 * p + 1)
        COMPUTE(1)
        barrier_nodrain();              // all waves done reading bufs
        if (nxt < SSN)          { WRITE_W(w0, 0) }
        if (nxt + 1 < SSN)      { WRITE_W(w1, 1) }
        barrier_nodrain();              // staged tiles visible
    }
    if (SSN & 1) {                      // odd tail: one ss from buf0
        LOAD_A(SSN - 1)
        COMPUTE(0)
    }

    // D layout: col = lane&15 (m), row = (lane>>4)*4 + reg (b)   [m89/m91]
    float* pz = partial + (size_t)kz * (B_ * M_);
#pragma unroll
    for (int n = 0; n < 3; ++n) {
        const int m = mt * BN + n * 16 + r16;
#pragma unroll
        for (int r = 0; r < 4; ++r) {
            const int b = wv * 16 + kg * 4 + r;
            pz[(size_t)b * M_ + m] = acc[n][r];
        }
    }
}

// ---------------- post: reduce_k | mlp_gemm (block-partitioned) -------------
__global__ __launch_bounds__(256) void post(const float* __restrict__ pp,
                                            const float* __restrict__ EP,
                                            const float* __restrict__ Wm,
                                            float* __restrict__ out) {
    const int bid = blockIdx.x;
    if (bid < 1536) {
        int t = bid * 256 + threadIdx.x;
        int i = t % (B_ * M_);
        int zc = t / (B_ * M_);
        float s = 0.f;
#pragma unroll
        for (int z = zc * (KSPLIT / ZC); z < (zc + 1) * (KSPLIT / ZC); ++z)
            s += pp[(size_t)z * (B_ * M_) + i];
        atomicAdd(out + i, 0.1f * s);
    } else {
        const int wid   = ((bid - 1536) * 256 + threadIdx.x) >> 6;  // 0..383
        const int lane  = threadIdx.x & 63;
        const int bt    = wid & 7;
        const int mt    = wid >> 3;
        const int row16 = lane & 15;
        const int kgrp  = lane >> 4;
        const float* Arow = EP + (size_t)(bt*16 + row16) * (2*E_);
        const float* Brow = Wm + (size_t)(mt*16 + row16) * (2*E_);
        f32x4 acc = {};
        for (int k0 = 0; k0 < 2*E_; k0 += 32) {
            bf16x8 af = cvt8(Arow + k0 + kgrp*8);
            bf16x8 bv = cvt8(Brow + k0 + kgrp*8);
            acc = __builtin_amdgcn_mfma_f32_16x16x32_bf16(af, bv, acc, 0, 0, 0);
        }
        const int m = mt*16 + row16;
#pragma unroll
        for (int r = 0; r < 4; ++r) {
            const int b = bt*16 + kgrp*4 + r;
            atomicAdd(out + b * M_ + m, 0.9f * acc[r]);
        }
    }
}

extern "C" void kernel_launch(void* const* d_in, const int* in_sizes, int n_in,
                              void* d_out, int out_size, void* d_ws, size_t ws_size,
                              hipStream_t stream) {
    const float* se    = (const float*)d_in[0];
    const int*   be    = (const int*)  d_in[1];
    const float* mlp_w = (const float*)d_in[2];
    const float* mlp_b = (const float*)d_in[3];
    const float* fk_w  = (const float*)d_in[4];
    const float* fk_b  = (const float*)d_in[5];
    float* out = (float*)d_out;
    float* ep  = (float*)d_ws;                  // event_pair [128][1536] f32
    float* pp  = ep + (size_t)B_ * 2 * E_;      // partials [KSPLIT][128][768] f32
    __bf16* apk = (__bf16*)(pp + (size_t)KSPLIT * B_ * M_);  // packed A bf16

    const int be_stride = (in_sizes[1] == B_ * 4 * 2) ? 2 : 1;

    prep<<<3584, 256, 0, stream>>>(mlp_b, fk_b, se, be, be_stride, out, ep, apk);
    fk_gemm<<<MTN * KSPLIT, 512, 0, stream>>>(apk, fk_w, pp);
    post<<<1632, 256, 0, stream>>>(pp, ep, mlp_w, out);
}

// Round 22
// 165.638 us; speedup vs baseline: 1.0694x; 1.0694x over previous
//
#include <hip/hip_runtime.h>
#include <hip/hip_bf16.h>

#define B_ 128
#define S_ 196
#define E_ 768
#define M_ 768
#define KTOT (S_*E_)            // 150528
#define BK 256                  // k per superstep
#define SS_TOTAL (KTOT/BK)      // 588
#define KSPLIT 32
#define BN 48                   // m-rows per workgroup
#define MTN (M_/BN)             // 16
#define PITCH 528               // fk LDS row pitch bytes
#define ZC 4                    // z-chunks in reduce
#define NPACK (SS_TOTAL*8)      // 4704 pack units (ss,bt)
#define PACKB (NPACK/4)         // 1176 pack blocks (4 waves each)

typedef __bf16 bf16x8 __attribute__((ext_vector_type(8)));
typedef __bf16 bf16x4 __attribute__((ext_vector_type(4)));
typedef float  f32x4  __attribute__((ext_vector_type(4)));

__device__ inline bf16x8 cvt8(const float* __restrict__ p) {
    float4 a = *(const float4*)p;
    float4 b = *(const float4*)(p + 4);
    bf16x8 r;
    r[0] = (__bf16)a.x; r[1] = (__bf16)a.y; r[2] = (__bf16)a.z; r[3] = (__bf16)a.w;
    r[4] = (__bf16)b.x; r[5] = (__bf16)b.y; r[6] = (__bf16)b.z; r[7] = (__bf16)b.w;
    return r;
}

// Barrier WITHOUT the implicit vmcnt(0) drain __syncthreads() carries.
__device__ inline void barrier_nodrain() {
    asm volatile("s_waitcnt lgkmcnt(0)" ::: "memory");
    __builtin_amdgcn_s_barrier();
}

// ---------------- prep: init_out | event_pool | pack_a --------------------
// pack_a via LDS transpose: each WAVE packs one (ss,bt) unit.
//  1) COALESCED read: 16 rows x 1KB (one float4 wave-load per row)
//     -- replaces the 16-way-scattered 64B gather (the R7 disease, on prep).
//  2) cvt f32->bf16, stage in wave-private 8KB LDS, swizzle byte^((row&7)<<4)
//     (emit-read banks 4*(kg^row) -> uniform 8/group = b128 minimum).
//  3) emit packed chunks as contiguous 1KB stores (layout unchanged:
//     chunk c = ((ss*8+bt)*8+kf)*64+lane holds
//     A[bt*16+(lane&15)][ss*256 + kf*32 + (lane>>4)*8 .. +8)).
// Wave-private regions -> no barriers; DS ops are wave-ordered.
__global__ __launch_bounds__(256) void prep(const float* __restrict__ mlp_b,
                     const float* __restrict__ fk_b,
                     const float* __restrict__ A,
                     const int* __restrict__ BE, int be_stride,
                     float* __restrict__ out,
                     float* __restrict__ EP,
                     __bf16* __restrict__ Apk) {
    __shared__ __align__(16) char Plds[4][16 * 512];   // 8KB per wave
    const int bid = blockIdx.x;
    if (bid < 384) {
        int i = bid * 256 + threadIdx.x;
        int m = i % M_;
        out[i] = 0.9f * mlp_b[m] + 0.1f * fk_b[m];
    } else if (bid < 512) {
        int b = bid - 384;
        int s1 = BE[(b*4 + 0) * be_stride];
        int e1 = BE[(b*4 + 1) * be_stride];
        int s2 = BE[(b*4 + 2) * be_stride];
        int e2 = BE[(b*4 + 3) * be_stride];
        float inv1 = 1.0f / (float)(e1 - s1);
        float inv2 = 1.0f / (float)(e2 - s2);
        for (int c = threadIdx.x; c < E_; c += 256) {
            float sum1 = 0.f, sum2 = 0.f;
            for (int s = s1; s < e1; ++s) sum1 += A[((size_t)b * S_ + s) * E_ + c];
            for (int s = s2; s < e2; ++s) sum2 += A[((size_t)b * S_ + s) * E_ + c];
            EP[b * (2*E_) + c]       = sum1 * inv1;
            EP[b * (2*E_) + E_ + c]  = sum2 * inv2;
        }
    } else {
        const int wv   = threadIdx.x >> 6;
        const int lane = threadIdx.x & 63;
        const int unit = (bid - 512) * 4 + wv;     // 0..4703
        const int ss = unit >> 3;
        const int bt = unit & 7;
        char* lds = &Plds[wv][0];

        // stage: 16 coalesced row-loads, cvt, swizzled LDS write
#pragma unroll
        for (int r = 0; r < 16; ++r) {
            const float* src = A + (size_t)(bt * 16 + r) * KTOT + ss * BK + lane * 4;
            float4 v = *(const float4*)src;
            bf16x4 h;
            h[0] = (__bf16)v.x; h[1] = (__bf16)v.y;
            h[2] = (__bf16)v.z; h[3] = (__bf16)v.w;
            *(bf16x4*)(lds + r * 512 + ((lane * 8) ^ ((r & 7) << 4))) = h;
        }
        // emit: swizzled LDS read -> contiguous 1KB packed stores
        const int r16 = lane & 15;
        const int kg  = lane >> 4;
#pragma unroll
        for (int kf = 0; kf < 8; ++kf) {
            bf16x8 x = *(const bf16x8*)(lds + r16 * 512 +
                        ((kf * 64 + kg * 16) ^ ((r16 & 7) << 4)));
            *(bf16x8*)(Apk + ((size_t)unit * 8 + kf) * 512 + lane * 8) = x;
        }
    }
}

// ---------------- fk_gemm: R14 verbatim (best = 165.8 us) ------------------
#define LOAD_A(AREG, sl)                                                      \
    _Pragma("unroll")                                                         \
    for (int kf = 0; kf < 8; ++kf)                                            \
        AREG[kf] = *(const bf16x8*)(abase + (size_t)(sl) * 32768 + kf * 512);

#define LOAD_W(sl)                                                            \
    _Pragma("unroll")                                                         \
    for (int i = 0; i < 6; ++i)                                               \
        w[i] = *(const float4*)(wbase + (size_t)i * KTOT + (size_t)(sl) * BK);

#define WRITE_W(buf)                                                          \
    _Pragma("unroll")                                                         \
    for (int i = 0; i < 6; ++i) {                                             \
        bf16x4 h;                                                             \
        h[0] = (__bf16)w[i].x; h[1] = (__bf16)w[i].y;                         \
        h[2] = (__bf16)w[i].z; h[3] = (__bf16)w[i].w;                         \
        *(bf16x4*)(&Wlds[buf][0] + wb + i * PITCH) = h;                       \
    }

#define COMPUTE(AREG, buf)                                                    \
    _Pragma("unroll")                                                         \
    for (int kf = 0; kf < 8; ++kf) {                                          \
        _Pragma("unroll")                                                     \
        for (int n = 0; n < 3; ++n) {                                         \
            bf16x8 wf = *(const bf16x8*)(&Wlds[buf][0] +                      \
                        (n * 16 + r16) * PITCH + kf * 64 + kg * 16);          \
            acc[n] = __builtin_amdgcn_mfma_f32_16x16x32_bf16(AREG[kf], wf,    \
                                                             acc[n], 0, 0, 0);\
        }                                                                     \
    }

__global__ __launch_bounds__(512, 4) void fk_gemm(const __bf16* __restrict__ Apk,
                                                  const float* __restrict__ W,
                                                  float* __restrict__ partial) {
    __shared__ __align__(16) char Wlds[2][BN * PITCH];  // 2 x 25,344 B

    const int wg   = blockIdx.x;        // 0..511
    const int xcd  = wg & 7;            // wg -> XCD round-robin (m09)
    const int slot = wg >> 3;           // 0..63 per-XCD sequence
    const int kz   = (slot >> 4) * 8 + xcd;  // 4 kz groups per XCD
    const int mt   = slot & 15;         // 16 mt-wgs per kz, dispatch-adjacent
    const int ss0 = (SS_TOTAL * kz) / KSPLIT;
    const int SSN = (SS_TOTAL * (kz + 1)) / KSPLIT - ss0;   // 18 or 19

    const int tid = threadIdx.x;
    const int wv  = tid >> 6;           // 0..7 = b-tile
    const int lane = tid & 63;
    const int r16 = lane & 15;
    const int kg  = lane >> 4;

    const float*  wbase = W + (size_t)(mt * BN + wv * 6) * KTOT
                            + (size_t)ss0 * BK + lane * 4;
    const int     wb    = (wv * 6) * PITCH + lane * 8;
    const __bf16* abase = Apk + ((size_t)ss0 * 8 + wv) * 4096 + lane * 8;

    f32x4 acc[3] = {};
    float4 w[6];
    bf16x8 aA[8], aB[8];

    // prologue: stage ss0 into buf0; preload A(0); W(1) in flight
    LOAD_W(0)
    WRITE_W(0)
    LOAD_A(aA, 0)
    LOAD_W(1)
    barrier_nodrain();

    int sl = 0;
    for (; sl + 1 < SSN; sl += 2) {
        // even: compute ss sl from buf0; stage W(sl+1) -> buf1
        LOAD_A(aB, sl + 1)
        COMPUTE(aA, 0)
        WRITE_W(1)                      // W(sl+1), loaded ~1 ss ago
        const bool more2 = (sl + 2 < SSN);
        if (more2) { LOAD_W(sl + 2) }
        barrier_nodrain();
        // odd: compute ss sl+1 from buf1; stage W(sl+2) -> buf0
        if (more2) { LOAD_A(aA, sl + 2) }
        COMPUTE(aB, 1)
        if (more2) {
            WRITE_W(0)                  // W(sl+2), loaded ~1 ss ago
            if (sl + 3 < SSN) { LOAD_W(sl + 3) }
            barrier_nodrain();
        }
    }
    if (SSN & 1) {  // leftover even ss in buf0 with aA preloaded
        COMPUTE(aA, 0)
    }

    // D layout: col = lane&15 (m), row = (lane>>4)*4 + reg (b)   [m89/m91]
    float* pz = partial + (size_t)kz * (B_ * M_);
#pragma unroll
    for (int n = 0; n < 3; ++n) {
        const int m = mt * BN + n * 16 + r16;
#pragma unroll
        for (int r = 0; r < 4; ++r) {
            const int b = wv * 16 + kg * 4 + r;
            pz[(size_t)b * M_ + m] = acc[n][r];
        }
    }
}

// ---------------- post: reduce_k | mlp_gemm (block-partitioned) -------------
__global__ __launch_bounds__(256) void post(const float* __restrict__ pp,
                                            const float* __restrict__ EP,
                                            const float* __restrict__ Wm,
                                            float* __restrict__ out) {
    const int bid = blockIdx.x;
    if (bid < 1536) {
        int t = bid * 256 + threadIdx.x;
        int i = t % (B_ * M_);
        int zc = t / (B_ * M_);
        float s = 0.f;
#pragma unroll
        for (int z = zc * (KSPLIT / ZC); z < (zc + 1) * (KSPLIT / ZC); ++z)
            s += pp[(size_t)z * (B_ * M_) + i];
        atomicAdd(out + i, 0.1f * s);
    } else {
        const int wid   = ((bid - 1536) * 256 + threadIdx.x) >> 6;  // 0..383
        const int lane  = threadIdx.x & 63;
        const int bt    = wid & 7;
        const int mt    = wid >> 3;
        const int row16 = lane & 15;
        const int kgrp  = lane >> 4;
        const float* Arow = EP + (size_t)(bt*16 + row16) * (2*E_);
        const float* Brow = Wm + (size_t)(mt*16 + row16) * (2*E_);
        f32x4 acc = {};
        for (int k0 = 0; k0 < 2*E_; k0 += 32) {
            bf16x8 af = cvt8(Arow + k0 + kgrp*8);
            bf16x8 bv = cvt8(Brow + k0 + kgrp*8);
            acc = __builtin_amdgcn_mfma_f32_16x16x32_bf16(af, bv, acc, 0, 0, 0);
        }
        const int m = mt*16 + row16;
#pragma unroll
        for (int r = 0; r < 4; ++r) {
            const int b = bt*16 + kgrp*4 + r;
            atomicAdd(out + b * M_ + m, 0.9f * acc[r]);
        }
    }
}

extern "C" void kernel_launch(void* const* d_in, const int* in_sizes, int n_in,
                              void* d_out, int out_size, void* d_ws, size_t ws_size,
                              hipStream_t stream) {
    const float* se    = (const float*)d_in[0];
    const int*   be    = (const int*)  d_in[1];
    const float* mlp_w = (const float*)d_in[2];
    const float* mlp_b = (const float*)d_in[3];
    const float* fk_w  = (const float*)d_in[4];
    const float* fk_b  = (const float*)d_in[5];
    float* out = (float*)d_out;
    float* ep  = (float*)d_ws;                  // event_pair [128][1536] f32
    float* pp  = ep + (size_t)B_ * 2 * E_;      // partials [KSPLIT][128][768] f32
    __bf16* apk = (__bf16*)(pp + (size_t)KSPLIT * B_ * M_);  // packed A bf16

    const int be_stride = (in_sizes[1] == B_ * 4 * 2) ? 2 : 1;

    prep<<<512 + PACKB, 256, 0, stream>>>(mlp_b, fk_b, se, be, be_stride, out, ep, apk);
    fk_gemm<<<MTN * KSPLIT, 512, 0, stream>>>(apk, fk_w, pp);
    post<<<1632, 256, 0, stream>>>(pp, ep, mlp_w, out);
}